// Round 6
// baseline (72.713 us; speedup 1.0000x reference)
//
#include <hip/hip_runtime.h>
#include <math.h>

#define BB 4
#define RR 1024
#define NN 100
#define NROI (BB * RR)

// packed best: high 32 = float bits of IoU (>=0, monotone), low 32 = ~gt_idx
// => u64 max picks highest IoU; on exact tie, smallest gt index (argmax-first).
#define INIT_PACK 0x00000000FFFFFFFFull

// corner i of a rect; sign conv. matches reference lxs=[.5,-.5,-.5,.5], lys=[.5,.5,-.5,-.5]
__device__ __forceinline__ void corner_of(int i, float cx0, float cy0, float dx, float dy,
                                          float c, float s, float& X, float& Y) {
    float sx = (i == 0 || i == 3) ? 0.5f : -0.5f;
    float sy = (i <= 1) ? 0.5f : -0.5f;
    float lx = sx * dx, ly = sy * dy;
    X = cx0 + lx * c - ly * s;
    Y = cy0 + lx * s + ly * c;
}

// One wave per ROI. No LDS, no __syncthreads.
//  - cheap z/circle test: lane l tests GT l and GT 64+l -> two ballots
//  - survivors popped two at a time: half-wave 0 -> first, half-wave 1 -> second;
//    24 polygon vertex candidates one-per-lane within each 32-lane half
//    (validated lane-parallel eval from R4/R5, unchanged math)
//  - running best in registers (packed u64), final cross-half merge via shuffle
//  - outputs written by distributed lanes
__global__ __launch_bounds__(256) void sampling_target_wave(
    const float* __restrict__ rois,   // (B,R,7)
    const int*   __restrict__ labels, // (B,R)
    const float* __restrict__ gts,    // (B,N,8)
    float*       __restrict__ out)
{
    const int r    = (int)((blockIdx.x * blockDim.x + threadIdx.x) >> 6);  // wave id = roi id
    const int lane = threadIdx.x & 63;
    if (r >= NROI) return;
    const int b = r >> 10;                       // RR = 1024
    const float* gbase = gts + b * NN * 8;

    // ROI params: wave-broadcast loads (single fetch each)
    const float* A = rois + r * 7;
    const float ax = A[0], ay = A[1], az = A[2];
    const float adx = A[3], ady = A[4], adz = A[5], aang = A[6];
    const float ra   = 0.5f * sqrtf(adx * adx + ady * ady);
    const float azlo = az - adz * 0.5f, azhi = az + adz * 0.5f;

    // ---- cheap reject: 100 GTs in 2 ballot rounds ----
    unsigned long long m0, m1;
    {
        unsigned long long mm[2];
#pragma unroll
        for (int it = 0; it < 2; it++) {
            int n = it * 64 + lane;
            bool pass = false;
            if (n < NN) {
                const float* G = gbase + n * 8;
                float gx = G[0], gy = G[1], gz = G[2];
                float gdx = G[3], gdy = G[4], gdz = G[5];
                float oh = fminf(azhi, gz + gdz * 0.5f) - fmaxf(azlo, gz - gdz * 0.5f);
                float dxc = ax - gx, dyc = ay - gy;
                float rb = 0.5f * sqrtf(gdx * gdx + gdy * gdy);
                float rr = ra + rb;
                pass = (oh > 0.0f) && (dxc * dxc + dyc * dyc <= rr * rr);
            }
            mm[it] = __ballot(pass);
        }
        m0 = mm[0]; m1 = mm[1];
    }

    const float acs = cosf(aang), asn = sinf(aang);
    const int half = lane >> 5;
    const int l32  = lane & 31;

    unsigned long long best = INIT_PACK;

    // ---- dense eval: two survivors per iteration (one per half-wave) ----
    while (m0 | m1) {
        int na, nb = -1;
        if (m0) { na = __ffsll((unsigned long long)m0) - 1;      m0 &= m0 - 1; }
        else    { na = __ffsll((unsigned long long)m1) - 1 + 64; m1 &= m1 - 1; }
        if (m0)      { nb = __ffsll((unsigned long long)m0) - 1;      m0 &= m0 - 1; }
        else if (m1) { nb = __ffsll((unsigned long long)m1) - 1 + 64; m1 &= m1 - 1; }

        const int  myN    = half ? nb : na;
        const bool active = (myN >= 0);
        const float* G = gbase + (active ? myN : 0) * 8;   // half-broadcast loads
        float gx = G[0], gy = G[1], gz = G[2];
        float gdx = G[3], gdy = G[4], gdz = G[5], gang = G[6];
        float bcs = cosf(gang), bsn = sinf(gang);

        // my candidate vertex (lane slot = reference slot ordering)
        float ppx = 0.0f, ppy = 0.0f;
        bool val = false;
        if (l32 < 4) {                        // corners of A inside B
            corner_of(l32, ax, ay, adx, ady, acs, asn, ppx, ppy);
            float qx = ppx - gx, qy = ppy - gy;
            float lx = qx * bcs + qy * bsn;
            float ly = -qx * bsn + qy * bcs;
            val = (fabsf(lx) <= gdx * 0.5f + 1e-5f) && (fabsf(ly) <= gdy * 0.5f + 1e-5f);
        } else if (l32 < 8) {                 // corners of B inside A
            corner_of(l32 - 4, gx, gy, gdx, gdy, bcs, bsn, ppx, ppy);
            float qx = ppx - ax, qy = ppy - ay;
            float lx = qx * acs + qy * asn;
            float ly = -qx * asn + qy * acs;
            val = (fabsf(lx) <= adx * 0.5f + 1e-5f) && (fabsf(ly) <= ady * 0.5f + 1e-5f);
        } else if (l32 < 24) {                // edge ii of A x edge jj of B
            int e = l32 - 8, ii = e >> 2, jj = e & 3;
            float a1x, a1y, a2x, a2y, b1x, b1y, b2x, b2y;
            corner_of(ii, ax, ay, adx, ady, acs, asn, a1x, a1y);
            corner_of((ii + 1) & 3, ax, ay, adx, ady, acs, asn, a2x, a2y);
            corner_of(jj, gx, gy, gdx, gdy, bcs, bsn, b1x, b1y);
            corner_of((jj + 1) & 3, gx, gy, gdx, gdy, bcs, bsn, b2x, b2y);
            float d1x = a2x - a1x, d1y = a2y - a1y;
            float d2x = b2x - b1x, d2y = b2y - b1y;
            float denom = d1x * d2y - d1y * d2x;
            float fx = b1x - a1x, fy = b1y - a1y;
            float safe = (fabsf(denom) > 1e-8f) ? denom : 1e-8f;
            float t = (fx * d2y - fy * d2x) / safe;
            float u = (fx * d1y - fy * d1x) / safe;
            ppx = a1x + t * d1x;
            ppy = a1y + t * d1y;
            val = (fabsf(denom) > 1e-8f) && (t >= 0.0f) && (t <= 1.0f) && (u >= 0.0f) && (u <= 1.0f);
        }
        val = val && active;

        unsigned long long bm = __ballot(val);
        unsigned gm = half ? (unsigned)(bm >> 32) : (unsigned)(bm & 0xFFFFFFFFull);
        int nv = __popc(gm);

        float inter_bev = 0.0f;
        if (nv >= 3) {   // half-uniform branch; width-32 shuffles read own half only
            float sx = val ? ppx : 0.0f;
            float sy = val ? ppy : 0.0f;
#pragma unroll
            for (int off = 16; off; off >>= 1) {
                sx += __shfl_xor(sx, off, 32);
                sy += __shfl_xor(sy, off, 32);
            }
            float cx = sx / (float)nv, cy = sy / (float)nv;

            float myAng = val ? atan2f(ppy - cy, ppx - cx) : 1e9f;

            // successor in (angle, index) order, index-only tracking;
            // ascending j + strict < == reference's stable-argsort tie rules
            float sAng = 1e30f; int sIdx = 0; bool found = false;
            float gAng = 1e30f; int gIdx = 0;
#pragma unroll
            for (int j = 0; j < 24; j++) {
                float aj = __shfl(myAng, j, 32);
                if (aj < 1e8f) {
                    bool greater = (aj > myAng) || (aj == myAng && j > l32);
                    if (greater && aj < sAng) { sAng = aj; sIdx = j; found = true; }
                    if (aj < gAng) { gAng = aj; gIdx = j; }
                }
            }
            int qi = found ? sIdx : gIdx;
            float qx = __shfl(ppx, qi, 32);
            float qy = __shfl(ppy, qi, 32);
            float contrib = val ? (ppx * qy - qx * ppy) : 0.0f;
#pragma unroll
            for (int off = 16; off; off >>= 1)
                contrib += __shfl_xor(contrib, off, 32);
            inter_bev = 0.5f * fabsf(contrib);
        }

        if (active) {
            float oh = fminf(azhi, gz + gdz * 0.5f) - fmaxf(azlo, gz - gdz * 0.5f); // >0 by cheap pass
            float inter = inter_bev * oh;
            float va = adx * ady * adz;
            float vb = gdx * gdy * gdz;
            float v = inter / fmaxf(va + vb - inter, 1e-6f);
            unsigned long long packed =
                ((unsigned long long)__float_as_uint(v) << 32) | (unsigned)(~(unsigned)myN);
            best = (packed > best) ? packed : best;
        }
    }

    // merge the two halves (u64 shuffle = 2 bpermutes)
    {
        unsigned long long other = __shfl(best, lane ^ 32, 64);
        best = (other > best) ? other : best;
    }

    float mo = __uint_as_float((unsigned)(best >> 32));
    int besti = (int)(~(unsigned)(best & 0xFFFFFFFFu));

    // ---- distributed output writes (global->global, L1-hot) ----
    float* out_rois = out;                    // NROI*7
    float* out_gor  = out + NROI * 7;         // NROI*8
    float* out_max  = out_gor + NROI * 8;     // NROI
    float* out_lab  = out_max + NROI;         // NROI
    float* out_msk  = out_lab + NROI;         // NROI

    if (lane < 7) {
        out_rois[r * 7 + lane] = A[lane];
    } else if (lane < 15) {
        int k = lane - 7;
        out_gor[r * 8 + k] = gbase[besti * 8 + k];
    } else if (lane == 15) {
        out_max[r] = mo;
    } else if (lane == 16) {
        out_lab[r] = (float)labels[r];
    } else if (lane == 17) {
        out_msk[r] = (mo > 0.55f) ? 1.0f : 0.0f;
    }
}

extern "C" void kernel_launch(void* const* d_in, const int* in_sizes, int n_in,
                              void* d_out, int out_size, void* d_ws, size_t ws_size,
                              hipStream_t stream) {
    const float* rois   = (const float*)d_in[0];  // (4,1024,7) f32
    const int*   labels = (const int*)d_in[1];    // (4,1024) i32
    const float* gts    = (const float*)d_in[2];  // (4,100,8) f32
    float* out = (float*)d_out;

    // one wave (64 lanes) per ROI: 4096 waves = 1024 blocks x 256 threads
    hipLaunchKernelGGL(sampling_target_wave, dim3(NROI / 4), dim3(256), 0, stream,
                       rois, labels, gts, out);
}

// Round 7
// 68.107 us; speedup vs baseline: 1.0676x; 1.0676x over previous
//
#include <hip/hip_runtime.h>
#include <math.h>

#define BB 4
#define RR 1024
#define NN 100
#define NROI (BB * RR)
#define RPB 2                      // ROIs per block -> 2048 blocks = 8/CU, whole grid co-resident
#define PPB (RPB * NN)             // 200 pairs per block
#define NBLK (NROI / RPB)

// packed best: high 32 = float bits of IoU (>=0, monotone), low 32 = ~gt_idx
// => u64 max picks highest IoU; exact tie -> smallest gt index (argmax-first).
#define INIT_PACK 0x00000000FFFFFFFFull

// corner i sign conv. matches reference lxs=[.5,-.5,-.5,.5], lys=[.5,.5,-.5,-.5]
__device__ __forceinline__ void corner_of(int i, float cx0, float cy0, float dx, float dy,
                                          float c, float s, float& X, float& Y) {
    float sx = (i == 0 || i == 3) ? 0.5f : -0.5f;
    float sy = (i <= 1) ? 0.5f : -0.5f;
    float lx = sx * dx, ly = sy * dy;
    X = cx0 + lx * c - ly * s;
    Y = cy0 + lx * s + ly * c;
}

// Fused, precompute-heavy kernel. Block owns 2 ROIs of one batch.
// Stage: 100 threads precompute per-GT trig/corners/radius/z-extents/volume ONCE
//        (identical FP expressions as reference -> bitwise-same values);
//        2 threads precompute per-ROI equivalents.
// Phase A: 200 cheap tests (no sqrt/trig, all precomputed), LDS worklist.
// Phase B: one surviving pair per 32-lane group (validated R4/R5 lane-parallel
//          polygon eval); corners read from LDS, no trig except atan2f.
// Phase C: distributed output writes.
__global__ __launch_bounds__(256) void sampling_target_fused(
    const float* __restrict__ rois,   // (B,R,7)
    const int*   __restrict__ labels, // (B,R)
    const float* __restrict__ gts,    // (B,N,8)
    float*       __restrict__ out)
{
    // per-GT precomputed (stride-1 arrays: conflict-free)
    __shared__ float s_gx[NN], s_gy[NN], s_gzlo[NN], s_gzhi[NN], s_grb[NN];
    __shared__ float s_bcs[NN], s_bsn[NN], s_bhx[NN], s_bhy[NN], s_vb[NN];
    __shared__ float s_gcx[4][NN], s_gcy[4][NN];      // B corners
    // per-ROI precomputed
    __shared__ float s_ax[RPB], s_ay[RPB], s_azlo[RPB], s_azhi[RPB], s_ara[RPB];
    __shared__ float s_acs[RPB], s_asn[RPB], s_ahx[RPB], s_ahy[RPB], s_va[RPB];
    __shared__ float s_acx[RPB][4], s_acy[RPB][4];
    __shared__ int   s_list[PPB];
    __shared__ int   s_cnt;
    __shared__ unsigned long long s_best[RPB];

    const int tid = threadIdx.x;
    const int roi0 = blockIdx.x * RPB;
    const int b = roi0 >> 10;                  // RR = 1024

    // ---- stage + precompute ----
    if (tid < NN) {
        const float4* gp = (const float4*)(gts + (b * NN + tid) * 8);
        float4 g0 = gp[0];          // x,y,z,dx
        float4 g1 = gp[1];          // dy,dz,heading,label
        float gx = g0.x, gy = g0.y, gz = g0.z, gdx = g0.w;
        float gdy = g1.x, gdz = g1.y, gang = g1.z;
        s_gx[tid] = gx; s_gy[tid] = gy;
        s_gzlo[tid] = gz - gdz * 0.5f;
        s_gzhi[tid] = gz + gdz * 0.5f;
        s_grb[tid] = 0.5f * sqrtf(gdx * gdx + gdy * gdy);
        float c = cosf(gang), s = sinf(gang);
        s_bcs[tid] = c; s_bsn[tid] = s;
        s_bhx[tid] = gdx * 0.5f + 1e-5f;
        s_bhy[tid] = gdy * 0.5f + 1e-5f;
        s_vb[tid] = gdx * gdy * gdz;
#pragma unroll
        for (int i = 0; i < 4; i++) {
            float X, Y;
            corner_of(i, gx, gy, gdx, gdy, c, s, X, Y);
            s_gcx[i][tid] = X; s_gcy[i][tid] = Y;
        }
    } else if (tid < NN + RPB) {
        int rl = tid - NN;
        const float* A = rois + (roi0 + rl) * 7;
        float ax = A[0], ay = A[1], az = A[2];
        float adx = A[3], ady = A[4], adz = A[5], aang = A[6];
        s_ax[rl] = ax; s_ay[rl] = ay;
        s_azlo[rl] = az - adz * 0.5f;
        s_azhi[rl] = az + adz * 0.5f;
        s_ara[rl] = 0.5f * sqrtf(adx * adx + ady * ady);
        float c = cosf(aang), s = sinf(aang);
        s_acs[rl] = c; s_asn[rl] = s;
        s_ahx[rl] = adx * 0.5f + 1e-5f;
        s_ahy[rl] = ady * 0.5f + 1e-5f;
        s_va[rl] = adx * ady * adz;
#pragma unroll
        for (int i = 0; i < 4; i++) {
            float X, Y;
            corner_of(i, ax, ay, adx, ady, c, s, X, Y);
            s_acx[rl][i] = X; s_acy[rl][i] = Y;
        }
        s_best[rl] = INIT_PACK;
    } else if (tid == NN + RPB) {
        s_cnt = 0;
    }
    __syncthreads();

    // ---- Phase A: cheap reject (precomputed radii/extents), compaction ----
    if (tid < PPB) {
        int rl = tid / NN;
        int n = tid - rl * NN;
        float oh = fminf(s_azhi[rl], s_gzhi[n]) - fmaxf(s_azlo[rl], s_gzlo[n]);
        float dxc = s_ax[rl] - s_gx[n], dyc = s_ay[rl] - s_gy[n];
        float rr = s_ara[rl] + s_grb[n];
        if (oh > 0.0f && dxc * dxc + dyc * dyc <= rr * rr) {
            int pos = atomicAdd(&s_cnt, 1);
            s_list[pos] = tid;      // capacity PPB: cannot overflow
        }
    }
    __syncthreads();

    // ---- Phase B: lane-parallel exact IoU, one pair per 32-lane group ----
    const int cnt = s_cnt;                     // ~3.5 expected -> 1 iter for 8 groups
    const int g = tid >> 5;
    const int lane = tid & 31;
    const int half = (tid >> 5) & 1;

    for (int i = g; i < cnt; i += 8) {
        int p = s_list[i];
        int rl = p / NN;
        int n = p - rl * NN;
        // group-broadcast LDS reads of precomputed params
        float ax = s_ax[rl], ay = s_ay[rl], acs = s_acs[rl], asn = s_asn[rl];
        float ahx = s_ahx[rl], ahy = s_ahy[rl];
        float gx = s_gx[n], gy = s_gy[n], bcs = s_bcs[n], bsn = s_bsn[n];
        float bhx = s_bhx[n], bhy = s_bhy[n];

        // my candidate vertex (lane slot = reference slot ordering)
        float ppx = 0.0f, ppy = 0.0f;
        bool val = false;
        if (lane < 4) {                        // corners of A inside B
            ppx = s_acx[rl][lane]; ppy = s_acy[rl][lane];
            float qx = ppx - gx, qy = ppy - gy;
            float lx = qx * bcs + qy * bsn;
            float ly = -qx * bsn + qy * bcs;
            val = (fabsf(lx) <= bhx) && (fabsf(ly) <= bhy);
        } else if (lane < 8) {                 // corners of B inside A
            int i4 = lane - 4;
            ppx = s_gcx[i4][n]; ppy = s_gcy[i4][n];
            float qx = ppx - ax, qy = ppy - ay;
            float lx = qx * acs + qy * asn;
            float ly = -qx * asn + qy * acs;
            val = (fabsf(lx) <= ahx) && (fabsf(ly) <= ahy);
        } else if (lane < 24) {                // edge ii of A x edge jj of B
            int e = lane - 8, ii = e >> 2, jj = e & 3;
            float a1x = s_acx[rl][ii],        a1y = s_acy[rl][ii];
            float a2x = s_acx[rl][(ii+1)&3],  a2y = s_acy[rl][(ii+1)&3];
            float b1x = s_gcx[jj][n],         b1y = s_gcy[jj][n];
            float b2x = s_gcx[(jj+1)&3][n],   b2y = s_gcy[(jj+1)&3][n];
            float d1x = a2x - a1x, d1y = a2y - a1y;
            float d2x = b2x - b1x, d2y = b2y - b1y;
            float denom = d1x * d2y - d1y * d2x;
            float fx = b1x - a1x, fy = b1y - a1y;
            float safe = (fabsf(denom) > 1e-8f) ? denom : 1e-8f;
            float t = (fx * d2y - fy * d2x) / safe;
            float u = (fx * d1y - fy * d1x) / safe;
            ppx = a1x + t * d1x;
            ppy = a1y + t * d1y;
            val = (fabsf(denom) > 1e-8f) && (t >= 0.0f) && (t <= 1.0f) && (u >= 0.0f) && (u <= 1.0f);
        }

        unsigned long long bm = __ballot(val);
        unsigned gm = half ? (unsigned)(bm >> 32) : (unsigned)(bm & 0xFFFFFFFFull);
        int nv = __popc(gm);

        float inter_bev = 0.0f;
        if (nv >= 3) {   // group-uniform; width-32 shuffles read own half only
            float sx = val ? ppx : 0.0f;
            float sy = val ? ppy : 0.0f;
#pragma unroll
            for (int off = 16; off; off >>= 1) {
                sx += __shfl_xor(sx, off, 32);
                sy += __shfl_xor(sy, off, 32);
            }
            float cx = sx / (float)nv, cy = sy / (float)nv;

            float myAng = val ? atan2f(ppy - cy, ppx - cx) : 1e9f;

            // successor in (angle, index) order, index-only tracking;
            // ascending j + strict < == reference stable-argsort tie rules
            float sAng = 1e30f; int sIdx = 0; bool found = false;
            float gAng = 1e30f; int gIdx = 0;
#pragma unroll
            for (int j = 0; j < 24; j++) {
                float aj = __shfl(myAng, j, 32);
                if (aj < 1e8f) {
                    bool greater = (aj > myAng) || (aj == myAng && j > lane);
                    if (greater && aj < sAng) { sAng = aj; sIdx = j; found = true; }
                    if (aj < gAng) { gAng = aj; gIdx = j; }
                }
            }
            int qi = found ? sIdx : gIdx;
            float qx = __shfl(ppx, qi, 32);
            float qy = __shfl(ppy, qi, 32);
            float contrib = val ? (ppx * qy - qx * ppy) : 0.0f;
#pragma unroll
            for (int off = 16; off; off >>= 1)
                contrib += __shfl_xor(contrib, off, 32);
            inter_bev = 0.5f * fabsf(contrib);
        }

        if (lane == 0) {
            float oh = fminf(s_azhi[rl], s_gzhi[n]) - fmaxf(s_azlo[rl], s_gzlo[n]); // >0 by Phase A
            float inter = inter_bev * oh;
            float v = inter / fmaxf(s_va[rl] + s_vb[n] - inter, 1e-6f);
            unsigned long long packed =
                ((unsigned long long)__float_as_uint(v) << 32) | (unsigned)(~(unsigned)n);
            atomicMax(&s_best[rl], packed);
        }
    }
    __syncthreads();

    // ---- Phase C: distributed output writes ----
    float* out_rois = out;                    // NROI*7
    float* out_gor  = out + NROI * 7;         // NROI*8
    float* out_max  = out_gor + NROI * 8;     // NROI
    float* out_lab  = out_max + NROI;         // NROI
    float* out_msk  = out_lab + NROI;         // NROI

    if (tid < RPB * 7) {                                  // rois copy (coalesced)
        out_rois[roi0 * 7 + tid] = rois[roi0 * 7 + tid];
    } else if (tid >= 16 && tid < 16 + RPB * 8) {         // gt_of_rois gather
        int k = tid - 16, rl = k >> 3, kk = k & 7;
        int besti = (int)(~(unsigned)(s_best[rl] & 0xFFFFFFFFu));
        out_gor[(roi0 + rl) * 8 + kk] = gts[(b * NN + besti) * 8 + kk];
    } else if (tid >= 32 && tid < 32 + RPB) {             // max_overlaps
        int rl = tid - 32;
        out_max[roi0 + rl] = __uint_as_float((unsigned)(s_best[rl] >> 32));
    } else if (tid >= 40 && tid < 40 + RPB) {             // labels
        int rl = tid - 40;
        out_lab[roi0 + rl] = (float)labels[roi0 + rl];
    } else if (tid >= 48 && tid < 48 + RPB) {             // reg_valid_mask
        int rl = tid - 48;
        float mo = __uint_as_float((unsigned)(s_best[rl] >> 32));
        out_msk[roi0 + rl] = (mo > 0.55f) ? 1.0f : 0.0f;
    }
}

extern "C" void kernel_launch(void* const* d_in, const int* in_sizes, int n_in,
                              void* d_out, int out_size, void* d_ws, size_t ws_size,
                              hipStream_t stream) {
    const float* rois   = (const float*)d_in[0];  // (4,1024,7) f32
    const int*   labels = (const int*)d_in[1];    // (4,1024) i32
    const float* gts    = (const float*)d_in[2];  // (4,100,8) f32
    float* out = (float*)d_out;

    hipLaunchKernelGGL(sampling_target_fused, dim3(NBLK), dim3(256), 0, stream,
                       rois, labels, gts, out);
}